// Round 8
// baseline (303.316 us; speedup 1.0000x reference)
//
#include <hip/hip_runtime.h>
#include <hip/hip_bf16.h>

#define NN      200000
#define D       64
#define NTILE   12500        // NN / 16
#define BKT_SH  8            // 256 rows per bucket
#define BKT_RW  256
#define NBKT    782          // ceil(NN / 256)
#define NCHUNK  512          // scatter blocks (epb ~6250, ~8 edges/bucket run)
#define NCOUNT  1024         // count blocks
#define L2CAP   6400         // max edges/bucket staged in LDS (51.2 KB; mean 4096, sigma ~64)
#define CPAD    16           // cursor padding (ints) -> one 64B line per bucket

typedef __attribute__((ext_vector_type(8))) short short8;
typedef __attribute__((ext_vector_type(4))) float f32x4;

__device__ inline unsigned short f32_to_bf16_rne(float x) {
    unsigned u = __float_as_uint(x);
    unsigned r = u + 0x7FFFu + ((u >> 16) & 1u);
    return (unsigned short)(r >> 16);
}
__device__ inline float bf16_bits_to_f32(unsigned short h) {
    return __uint_as_float(((unsigned)h) << 16);
}
__device__ inline unsigned pack2_bf16_rne(float lo, float hi) {
    unsigned a = __float_as_uint(lo);
    unsigned b = __float_as_uint(hi);
    a = a + 0x7FFFu + ((a >> 16) & 1u);
    b = b + 0x7FFFu + ((b >> 16) & 1u);
    return (a >> 16) | (b & 0xFFFF0000u);
}
__device__ inline float bf_lo(unsigned u) { return __uint_as_float(u << 16); }
__device__ inline float bf_hi(unsigned u) { return __uint_as_float(u & 0xFFFF0000u); }

// ---------------- utility kernels ----------------
__global__ __launch_bounds__(256) void zero_f4(float4* __restrict__ p, int n4) {
    int i = blockIdx.x * blockDim.x + threadIdx.x;
    if (i < n4) p[i] = make_float4(0.f, 0.f, 0.f, 0.f);
}
__global__ __launch_bounds__(256) void zero_i(int* __restrict__ p, int n) {
    int i = blockIdx.x * blockDim.x + threadIdx.x;
    if (i < n) p[i] = 0;
}
__global__ __launch_bounds__(256) void cvt_bf16(const float2* __restrict__ in,
                                                unsigned* __restrict__ out, int n) {
    int stride = gridDim.x * blockDim.x;
    for (int i = blockIdx.x * blockDim.x + threadIdx.x; i < n; i += stride) {
        float2 v = in[i];
        out[i] = pack2_bf16_rne(v.x, v.y);
    }
}

// ---------------- pass 1: bucket totals (LDS hist, padded global atomics) ----------------
__global__ __launch_bounds__(256) void bkt_count(const int* __restrict__ rows,
                                                 int* __restrict__ tot_p,
                                                 int E, int epb) {
    __shared__ int h[NBKT];
    for (int i = threadIdx.x; i < NBKT; i += 256) h[i] = 0;
    __syncthreads();
    int start = blockIdx.x * epb;
    int end   = min(E, start + epb);
    for (int e = start + threadIdx.x; e < end; e += 256)
        atomicAdd(&h[rows[e] >> BKT_SH], 1);
    __syncthreads();
    for (int i = threadIdx.x; i < NBKT; i += 256)
        if (h[i]) atomicAdd(&tot_p[i * CPAD], h[i]);
}

// ---------------- pass 2: single-block scan over 782 bucket totals ----------------
__global__ __launch_bounds__(1024) void bkt_scan(const int* __restrict__ tot_p,
                                                 int* __restrict__ bktstart,
                                                 int* __restrict__ cursor_p,
                                                 int* __restrict__ rp, int E) {
    __shared__ int s[1024];
    int t = threadIdx.x;
    int v = (t < NBKT) ? tot_p[t * CPAD] : 0;
    s[t] = v;
    __syncthreads();
    #pragma unroll
    for (int d = 1; d < 1024; d <<= 1) {
        int a = (t >= d) ? s[t - d] : 0;
        __syncthreads();
        s[t] += a;
        __syncthreads();
    }
    if (t < NBKT) {
        int ex = s[t] - v;
        bktstart[t] = ex;
        cursor_p[t * CPAD] = ex;
    }
    if (t == 0) { bktstart[NBKT] = E; rp[NN] = E; }
}

// ---------------- pass 3: scatter into bucket-ordered runs (padded cursors) ----------------
__global__ __launch_bounds__(256) void scatter_l1(const int* __restrict__ rows,
                                                  const int* __restrict__ cols,
                                                  const float* __restrict__ vals,
                                                  int* __restrict__ cursor_p,
                                                  int2* __restrict__ packed,
                                                  int E, int epb) {
    __shared__ int h[NBKT];
    __shared__ int base[NBKT];
    for (int i = threadIdx.x; i < NBKT; i += 256) h[i] = 0;
    __syncthreads();
    int start = blockIdx.x * epb;
    int end   = min(E, start + epb);
    for (int e = start + threadIdx.x; e < end; e += 256)
        atomicAdd(&h[rows[e] >> BKT_SH], 1);
    __syncthreads();
    for (int i = threadIdx.x; i < NBKT; i += 256) {
        int c = h[i];
        base[i] = c ? atomicAdd(&cursor_p[i * CPAD], c) : 0;
        h[i] = 0;
    }
    __syncthreads();
    for (int e = start + threadIdx.x; e < end; e += 256) {
        int r = rows[e];
        int b = r >> BKT_SH;
        int p = base[b] + atomicAdd(&h[b], 1);
        packed[p] = make_int2(cols[e] | ((r & (BKT_RW - 1)) << 18),
                              __float_as_int(vals[e]));
    }
}

// ---------------- pass 4: per-bucket in-place sort to exact CSR ----------------
__global__ __launch_bounds__(256) void sort_l2(const int* __restrict__ bktstart,
                                               int2* __restrict__ packed,
                                               int* __restrict__ rp) {
    __shared__ int2 sm[L2CAP];
    __shared__ int  cnt[BKT_RW];
    __shared__ int  cur[BKT_RW];
    int b = blockIdx.x;
    int s = bktstart[b];
    int e = bktstart[b + 1];
    int n = e - s;
    int t = threadIdx.x;
    cnt[t] = 0;
    __syncthreads();
    for (int i = t; i < n; i += 256) {
        int2 v = packed[s + i];
        sm[i] = v;
        atomicAdd(&cnt[(v.x >> 18) & (BKT_RW - 1)], 1);
    }
    __syncthreads();
    #pragma unroll
    for (int d = 1; d < BKT_RW; d <<= 1) {
        int a = (t >= d) ? cnt[t - d] : 0;
        __syncthreads();
        cnt[t] += a;
        __syncthreads();
    }
    {
        int ex = t ? cnt[t - 1] : 0;
        cur[t] = ex;
        int g = (b << BKT_SH) + t;
        if (g < NN) rp[g] = s + ex;
    }
    __syncthreads();
    for (int i = t; i < n; i += 256) {
        int2 v = sm[i];
        int  p = atomicAdd(&cur[(v.x >> 18) & (BKT_RW - 1)], 1);
        packed[s + p] = make_int2(v.x & 0x3FFFF, v.y);
    }
}

// ---------------- gather SpMM, 4 rows/wave, quarter-wave per row ----------------
template <int OUT_BF16>
__global__ __launch_bounds__(256) void spmm_q(const int* __restrict__ rp,
                                              const int2* __restrict__ packed,
                                              const uint2* __restrict__ ein,
                                              uint2* __restrict__ out_bf,
                                              float4* __restrict__ out_f32, int n) {
    int wave = (blockIdx.x * 256 + threadIdx.x) >> 6;
    int lane = threadIdx.x & 63;
    int l    = lane & 15;
    int row  = wave * 4 + (lane >> 4);

    float ax = 0.f, ay = 0.f, az = 0.f, aw = 0.f;
    int s = 0, e = 0;
    if (row < n) { s = rp[row]; e = rp[row + 1]; }

    for (int base = s; base < e; base += 16) {
        int cnt = e - base; if (cnt > 16) cnt = 16;
        int2 ev = make_int2(0, 0);
        if (l < cnt) ev = packed[base + l];
        int k = 0;
        for (; k + 4 <= cnt; k += 4) {
            int   c0 = __shfl(ev.x, k,     16), c1 = __shfl(ev.x, k + 1, 16);
            int   c2 = __shfl(ev.x, k + 2, 16), c3 = __shfl(ev.x, k + 3, 16);
            float v0 = __int_as_float(__shfl(ev.y, k,     16));
            float v1 = __int_as_float(__shfl(ev.y, k + 1, 16));
            float v2 = __int_as_float(__shfl(ev.y, k + 2, 16));
            float v3 = __int_as_float(__shfl(ev.y, k + 3, 16));
            uint2 g0 = ein[c0 * 16 + l];
            uint2 g1 = ein[c1 * 16 + l];
            uint2 g2 = ein[c2 * 16 + l];
            uint2 g3 = ein[c3 * 16 + l];
            ax += v0 * bf_lo(g0.x); ay += v0 * bf_hi(g0.x);
            az += v0 * bf_lo(g0.y); aw += v0 * bf_hi(g0.y);
            ax += v1 * bf_lo(g1.x); ay += v1 * bf_hi(g1.x);
            az += v1 * bf_lo(g1.y); aw += v1 * bf_hi(g1.y);
            ax += v2 * bf_lo(g2.x); ay += v2 * bf_hi(g2.x);
            az += v2 * bf_lo(g2.y); aw += v2 * bf_hi(g2.y);
            ax += v3 * bf_lo(g3.x); ay += v3 * bf_hi(g3.x);
            az += v3 * bf_lo(g3.y); aw += v3 * bf_hi(g3.y);
        }
        for (; k + 2 <= cnt; k += 2) {
            int   c0 = __shfl(ev.x, k, 16), c1 = __shfl(ev.x, k + 1, 16);
            float v0 = __int_as_float(__shfl(ev.y, k,     16));
            float v1 = __int_as_float(__shfl(ev.y, k + 1, 16));
            uint2 g0 = ein[c0 * 16 + l];
            uint2 g1 = ein[c1 * 16 + l];
            ax += v0 * bf_lo(g0.x); ay += v0 * bf_hi(g0.x);
            az += v0 * bf_lo(g0.y); aw += v0 * bf_hi(g0.y);
            ax += v1 * bf_lo(g1.x); ay += v1 * bf_hi(g1.x);
            az += v1 * bf_lo(g1.y); aw += v1 * bf_hi(g1.y);
        }
        if (k < cnt) {
            int   c0 = __shfl(ev.x, k, 16);
            float v0 = __int_as_float(__shfl(ev.y, k, 16));
            uint2 g0 = ein[c0 * 16 + l];
            ax += v0 * bf_lo(g0.x); ay += v0 * bf_hi(g0.x);
            az += v0 * bf_lo(g0.y); aw += v0 * bf_hi(g0.y);
        }
    }
    if (row < n) {
        if (OUT_BF16) {
            out_bf[(size_t)row * 16 + l] =
                make_uint2(pack2_bf16_rne(ax, ay), pack2_bf16_rne(az, aw));
        } else {
            out_f32[(size_t)row * 16 + l] = make_float4(ax, ay, az, aw);
        }
    }
}

// ---------------- fallback scatter SpMM (atomic path) ----------------
__global__ __launch_bounds__(256) void spmm_scatter(const int* __restrict__ rows,
                                                    const int* __restrict__ cols,
                                                    const float* __restrict__ vals,
                                                    const float* __restrict__ ein,
                                                    float* __restrict__ eout, int E) {
    int gid  = blockIdx.x * blockDim.x + threadIdx.x;
    int wid  = gid >> 6;
    int lane = threadIdx.x & 63;
    int nw   = (gridDim.x * blockDim.x) >> 6;
    for (int e = wid; e < E; e += nw) {
        int   r = rows[e];
        int   c = cols[e];
        float v = vals[e];
        float x = ein[(size_t)c * D + lane];
        unsafeAtomicAdd(&eout[(size_t)r * D + lane], v * x);
    }
}

// ---------------- MFMA fused 2-layer residual MLP + LayerNorm, in-place ----------------
__global__ __launch_bounds__(256) void mlp_mfma(float* __restrict__ e,
                                                const float* __restrict__ Ws,
                                                const float* __restrict__ bs,
                                                const float* __restrict__ gamma,
                                                const float* __restrict__ beta) {
    __shared__ float xp[4][16][68];
    int t  = threadIdx.x;
    int wv = t >> 6;
    int fr = t & 15;
    int fq = (t & 63) >> 4;

    short8 wh[2][4][2], wl[2][4][2];
    #pragma unroll
    for (int l = 0; l < 2; ++l)
        #pragma unroll
        for (int nt = 0; nt < 4; ++nt)
            #pragma unroll
            for (int kk = 0; kk < 2; ++kk) {
                const float* src = Ws + l * 4096 + (nt * 16 + fr) * 64 + kk * 32 + fq * 8;
                float4 a = *(const float4*)src;
                float4 b = *(const float4*)(src + 4);
                float v[8] = {a.x, a.y, a.z, a.w, b.x, b.y, b.z, b.w};
                short8 H, L;
                #pragma unroll
                for (int j = 0; j < 8; ++j) {
                    unsigned short hh = f32_to_bf16_rne(v[j]);
                    H[j] = hh;
                    L[j] = f32_to_bf16_rne(v[j] - bf16_bits_to_f32(hh));
                }
                wh[l][nt][kk] = H;
                wl[l][nt][kk] = L;
            }
    float bia0[4], bia1[4], gam[4], bet[4];
    #pragma unroll
    for (int nt = 0; nt < 4; ++nt) {
        bia0[nt] = bs[nt * 16 + fr];
        bia1[nt] = bs[64 + nt * 16 + fr];
        gam[nt]  = gamma[nt * 16 + fr];
        bet[nt]  = beta[nt * 16 + fr];
    }

    int wgid = blockIdx.x * 4 + wv;
    int nwv  = gridDim.x * 4;
    for (int tile = wgid; tile < NTILE; tile += nwv) {
        float* base = e + (size_t)tile * 16 * D;

        short8 xh[2], xl[2];
        #pragma unroll
        for (int kk = 0; kk < 2; ++kk) {
            const float* s = base + fr * D + kk * 32 + fq * 8;
            float4 a = *(const float4*)s;
            float4 b = *(const float4*)(s + 4);
            float v[8] = {a.x, a.y, a.z, a.w, b.x, b.y, b.z, b.w};
            #pragma unroll
            for (int j = 0; j < 8; ++j) {
                unsigned short hh = f32_to_bf16_rne(v[j]);
                xh[kk][j] = hh;
                xl[kk][j] = f32_to_bf16_rne(v[j] - bf16_bits_to_f32(hh));
            }
        }
        float xr[4][4];
        #pragma unroll
        for (int nt = 0; nt < 4; ++nt)
            #pragma unroll
            for (int j = 0; j < 4; ++j)
                xr[nt][j] = base[(fq * 4 + j) * D + nt * 16 + fr];

        f32x4 acc[4];
        #pragma unroll
        for (int nt = 0; nt < 4; ++nt) {
            acc[nt] = f32x4{bia0[nt], bia0[nt], bia0[nt], bia0[nt]};
            #pragma unroll
            for (int kk = 0; kk < 2; ++kk) {
                acc[nt] = __builtin_amdgcn_mfma_f32_16x16x32_bf16(xl[kk], wh[0][nt][kk], acc[nt], 0, 0, 0);
                acc[nt] = __builtin_amdgcn_mfma_f32_16x16x32_bf16(xh[kk], wl[0][nt][kk], acc[nt], 0, 0, 0);
                acc[nt] = __builtin_amdgcn_mfma_f32_16x16x32_bf16(xh[kk], wh[0][nt][kk], acc[nt], 0, 0, 0);
            }
        }
        float y1[4][4];
        #pragma unroll
        for (int nt = 0; nt < 4; ++nt)
            #pragma unroll
            for (int j = 0; j < 4; ++j) {
                y1[nt][j] = fmaxf(acc[nt][j], 0.f) + xr[nt][j];
                xp[wv][fq * 4 + j][nt * 16 + fr] = y1[nt][j];
            }

        #pragma unroll
        for (int kk = 0; kk < 2; ++kk) {
            const float* s = &xp[wv][fr][kk * 32 + fq * 8];
            float4 a = *(const float4*)s;
            float4 b = *(const float4*)(s + 4);
            float v[8] = {a.x, a.y, a.z, a.w, b.x, b.y, b.z, b.w};
            #pragma unroll
            for (int j = 0; j < 8; ++j) {
                unsigned short hh = f32_to_bf16_rne(v[j]);
                xh[kk][j] = hh;
                xl[kk][j] = f32_to_bf16_rne(v[j] - bf16_bits_to_f32(hh));
            }
        }

        #pragma unroll
        for (int nt = 0; nt < 4; ++nt) {
            acc[nt] = f32x4{bia1[nt], bia1[nt], bia1[nt], bia1[nt]};
            #pragma unroll
            for (int kk = 0; kk < 2; ++kk) {
                acc[nt] = __builtin_amdgcn_mfma_f32_16x16x32_bf16(xl[kk], wh[1][nt][kk], acc[nt], 0, 0, 0);
                acc[nt] = __builtin_amdgcn_mfma_f32_16x16x32_bf16(xh[kk], wl[1][nt][kk], acc[nt], 0, 0, 0);
                acc[nt] = __builtin_amdgcn_mfma_f32_16x16x32_bf16(xh[kk], wh[1][nt][kk], acc[nt], 0, 0, 0);
            }
        }
        float y2[4][4];
        #pragma unroll
        for (int nt = 0; nt < 4; ++nt)
            #pragma unroll
            for (int j = 0; j < 4; ++j)
                y2[nt][j] = fmaxf(acc[nt][j], 0.f) + y1[nt][j];

        float sm[4], sq[4];
        #pragma unroll
        for (int j = 0; j < 4; ++j) {
            float s0 = 0.f, q0 = 0.f;
            #pragma unroll
            for (int nt = 0; nt < 4; ++nt) { s0 += y2[nt][j]; q0 += y2[nt][j] * y2[nt][j]; }
            sm[j] = s0; sq[j] = q0;
        }
        #pragma unroll
        for (int off = 1; off < 16; off <<= 1) {
            #pragma unroll
            for (int j = 0; j < 4; ++j) {
                sm[j] += __shfl_xor(sm[j], off);
                sq[j] += __shfl_xor(sq[j], off);
            }
        }
        #pragma unroll
        for (int j = 0; j < 4; ++j) {
            float mu  = sm[j] * (1.f / 64.f);
            float var = sq[j] * (1.f / 64.f) - mu * mu;
            float rs  = rsqrtf(var + 1e-5f);
            #pragma unroll
            for (int nt = 0; nt < 4; ++nt)
                base[(fq * 4 + j) * D + nt * 16 + fr] =
                    (y2[nt][j] - mu) * rs * gam[nt] + bet[nt];
        }
    }
}

extern "C" void kernel_launch(void* const* d_in, const int* in_sizes, int n_in,
                              void* d_out, int out_size, void* d_ws, size_t ws_size,
                              hipStream_t stream) {
    const int*   rows  = (const int*)d_in[0];
    const int*   cols  = (const int*)d_in[1];
    const float* vals  = (const float*)d_in[2];
    const float* ini   = (const float*)d_in[3];
    const float* Ws    = (const float*)d_in[4];
    const float* bs    = (const float*)d_in[5];
    const float* gamma = (const float*)d_in[6];
    const float* beta  = (const float*)d_in[7];
    float* out = (float*)d_out;
    int E = in_sizes[0];

    size_t inibf_b  = (size_t)NN * 32 * 4;                        // 25.6 MB
    size_t e1bf_b   = inibf_b;                                    // 25.6 MB
    size_t packed_b = ((size_t)E * 8 + 63) & ~(size_t)63;         // 25.6 MB
    size_t rp_b     = (((size_t)NN + 1) * 4 + 63) & ~(size_t)63;
    size_t bsrt_b   = (((size_t)NBKT + 1) * 4 + 63) & ~(size_t)63;
    size_t pad_b    = (size_t)NBKT * CPAD * 4;                    // 50 KB each
    size_t need     = inibf_b + e1bf_b + packed_b + rp_b + bsrt_b + 2 * pad_b;

    if (ws_size >= need) {
        char* w = (char*)d_ws;
        unsigned* ini_bf   = (unsigned*)w;  w += inibf_b;
        unsigned* e1_bf    = (unsigned*)w;  w += e1bf_b;
        int2*     packed   = (int2*)w;      w += packed_b;
        int*      rp       = (int*)w;       w += rp_b;
        int*      bktstart = (int*)w;       w += bsrt_b;
        int*      tot_p    = (int*)w;       w += pad_b;
        int*      cursor_p = (int*)w;

        int epb_c = (E + NCOUNT - 1) / NCOUNT;
        int epb_s = (E + NCHUNK - 1) / NCHUNK;
        cvt_bf16<<<2048, 256, 0, stream>>>((const float2*)ini, ini_bf, NN * 32);
        zero_i<<<(NBKT * CPAD + 255) / 256, 256, 0, stream>>>(tot_p, NBKT * CPAD);
        bkt_count<<<NCOUNT, 256, 0, stream>>>(rows, tot_p, E, epb_c);
        bkt_scan<<<1, 1024, 0, stream>>>(tot_p, bktstart, cursor_p, rp, E);
        scatter_l1<<<NCHUNK, 256, 0, stream>>>(rows, cols, vals, cursor_p, packed, E, epb_s);
        sort_l2<<<NBKT, 256, 0, stream>>>(bktstart, packed, rp);

        int waves = (NN + 3) / 4;
        int blocks = (waves + 3) / 4;
        spmm_q<1><<<blocks, 256, 0, stream>>>(rp, packed, (const uint2*)ini_bf,
                                              (uint2*)e1_bf, nullptr, NN);
        spmm_q<0><<<blocks, 256, 0, stream>>>(rp, packed, (const uint2*)e1_bf,
                                              nullptr, (float4*)out, NN);
    } else {
        float* e1 = (float*)d_ws;
        int n4 = out_size / 4;
        int zb = (n4 + 255) / 256;
        zero_f4<<<zb, 256, 0, stream>>>((float4*)e1,  n4);
        zero_f4<<<zb, 256, 0, stream>>>((float4*)out, n4);
        spmm_scatter<<<12800, 256, 0, stream>>>(rows, cols, vals, ini, e1, E);
        spmm_scatter<<<12800, 256, 0, stream>>>(rows, cols, vals, e1, out, E);
    }

    mlp_mfma<<<1563, 256, 0, stream>>>(out, Ws, bs, gamma, beta);
}

// Round 9
// 278.249 us; speedup vs baseline: 1.0901x; 1.0901x over previous
//
#include <hip/hip_runtime.h>
#include <hip/hip_bf16.h>

#define NN      200000
#define D       64
#define NTILE   12500        // NN / 16
#define BKT_SH  8            // 256 rows per bucket
#define BKT_RW  256
#define NBKT    782          // ceil(NN / 256)
#define NCHUNK  128          // edge-pass blocks (1024 threads each); epb = 25000
#define L2CAP   6656         // max edges/bucket staged in LDS (53 KB); avg 4096+pad~450
#define CPAD    16           // cursor padding (ints) -> one 64B line per bucket
#define RSENT   256          // sentinel r_local for pad edges

typedef __attribute__((ext_vector_type(8))) short short8;
typedef __attribute__((ext_vector_type(4))) float f32x4;

__device__ inline unsigned short f32_to_bf16_rne(float x) {
    unsigned u = __float_as_uint(x);
    unsigned r = u + 0x7FFFu + ((u >> 16) & 1u);
    return (unsigned short)(r >> 16);
}
__device__ inline float bf16_bits_to_f32(unsigned short h) {
    return __uint_as_float(((unsigned)h) << 16);
}
__device__ inline unsigned pack2_bf16_rne(float lo, float hi) {
    unsigned a = __float_as_uint(lo);
    unsigned b = __float_as_uint(hi);
    a = a + 0x7FFFu + ((a >> 16) & 1u);
    b = b + 0x7FFFu + ((b >> 16) & 1u);
    return (a >> 16) | (b & 0xFFFF0000u);
}
__device__ inline float bf_lo(unsigned u) { return __uint_as_float(u << 16); }
__device__ inline float bf_hi(unsigned u) { return __uint_as_float(u & 0xFFFF0000u); }

// ---------------- utility kernels ----------------
__global__ __launch_bounds__(256) void zero_f4(float4* __restrict__ p, int n4) {
    int i = blockIdx.x * blockDim.x + threadIdx.x;
    if (i < n4) p[i] = make_float4(0.f, 0.f, 0.f, 0.f);
}
__global__ __launch_bounds__(256) void zero_i(int* __restrict__ p, int n) {
    int i = blockIdx.x * blockDim.x + threadIdx.x;
    if (i < n) p[i] = 0;
}
__global__ __launch_bounds__(256) void cvt_bf16(const float2* __restrict__ in,
                                                unsigned* __restrict__ out, int n) {
    int stride = gridDim.x * blockDim.x;
    for (int i = blockIdx.x * blockDim.x + threadIdx.x; i < n; i += stride) {
        float2 v = in[i];
        out[i] = pack2_bf16_rne(v.x, v.y);
    }
}

// ---------------- pass 1: ALIGNED bucket totals (same partition as scatter) ----------------
template <int ALIGN>
__global__ __launch_bounds__(1024) void bkt_count(const int* __restrict__ rows,
                                                  int* __restrict__ tot_p,
                                                  int E, int epb) {
    __shared__ int h[NBKT];
    int t = threadIdx.x;
    for (int i = t; i < NBKT; i += 1024) h[i] = 0;
    __syncthreads();
    int start = blockIdx.x * epb;
    int end   = min(E, start + epb);
    for (int e = start + t; e < end; e += 1024)
        atomicAdd(&h[rows[e] >> BKT_SH], 1);
    __syncthreads();
    for (int i = t; i < NBKT; i += 1024) {
        int c   = h[i];
        int res = (c + ALIGN - 1) & ~(ALIGN - 1);
        if (res) atomicAdd(&tot_p[i * CPAD], res);
    }
}

// ---------------- pass 2: single-block scan over aligned bucket totals ----------------
__global__ __launch_bounds__(1024) void bkt_scan(const int* __restrict__ tot_p,
                                                 int* __restrict__ bktstart,
                                                 int* __restrict__ cursor_p) {
    __shared__ int s[1024];
    int t = threadIdx.x;
    int v = (t < NBKT) ? tot_p[t * CPAD] : 0;
    s[t] = v;
    __syncthreads();
    #pragma unroll
    for (int d = 1; d < 1024; d <<= 1) {
        int a = (t >= d) ? s[t - d] : 0;
        __syncthreads();
        s[t] += a;
        __syncthreads();
    }
    if (t < NBKT) {
        int ex = s[t] - v;
        bktstart[t] = ex;
        cursor_p[t * CPAD] = ex;
    }
    if (t == 0) bktstart[NBKT] = s[1023];   // = total aligned edges
}

// ---------------- pass 3: scatter into 64B-aligned bucket runs ----------------
template <int ALIGN>
__global__ __launch_bounds__(1024) void scatter_l1(const int* __restrict__ rows,
                                                   const int* __restrict__ cols,
                                                   const float* __restrict__ vals,
                                                   int* __restrict__ cursor_p,
                                                   int2* __restrict__ packed,
                                                   int E, int epb) {
    __shared__ int h[NBKT];
    __shared__ int base[NBKT];
    int t = threadIdx.x;
    for (int i = t; i < NBKT; i += 1024) h[i] = 0;
    __syncthreads();
    int start = blockIdx.x * epb;
    int end   = min(E, start + epb);
    for (int e = start + t; e < end; e += 1024)
        atomicAdd(&h[rows[e] >> BKT_SH], 1);
    __syncthreads();
    for (int i = t; i < NBKT; i += 1024) {
        int c   = h[i];
        int res = (c + ALIGN - 1) & ~(ALIGN - 1);
        int b0  = res ? atomicAdd(&cursor_p[i * CPAD], res) : 0;
        base[i] = b0;
        for (int j = c; j < res; ++j)            // sentinel pads (never consumed)
            packed[b0 + j] = make_int2(RSENT << 18, 0);
        h[i] = 0;                                // reuse as run cursor
    }
    __syncthreads();
    for (int e = start + t; e < end; e += 1024) {
        int r = rows[e];
        int b = r >> BKT_SH;
        int p = base[b] + atomicAdd(&h[b], 1);
        packed[p] = make_int2(cols[e] | ((r & (BKT_RW - 1)) << 18),
                              __float_as_int(vals[e]));
    }
}

// ---------------- pass 4: per-bucket in-place sort to exact CSR (drops pads) ----------------
__global__ __launch_bounds__(256) void sort_l2(const int* __restrict__ bktstart,
                                               int2* __restrict__ packed,
                                               int* __restrict__ rp,
                                               int* __restrict__ rpe) {
    __shared__ int2 sm[L2CAP];
    __shared__ int  cnt[BKT_RW];
    __shared__ int  cur[BKT_RW];
    int b = blockIdx.x;
    int s = bktstart[b];
    int e = bktstart[b + 1];
    int n = e - s;
    if (n > L2CAP) n = L2CAP;   // safety clamp (statistically unreachable)
    int t = threadIdx.x;
    cnt[t] = 0;
    __syncthreads();
    for (int i = t; i < n; i += 256) {
        int2 v = packed[s + i];
        sm[i] = v;
        int r = (v.x >> 18) & 0x1FF;
        if (r < BKT_RW) atomicAdd(&cnt[r], 1);
    }
    __syncthreads();
    #pragma unroll
    for (int d = 1; d < BKT_RW; d <<= 1) {       // inclusive scan over 256 bins
        int a = (t >= d) ? cnt[t - d] : 0;
        __syncthreads();
        cnt[t] += a;
        __syncthreads();
    }
    {
        int ex = t ? cnt[t - 1] : 0;
        cur[t] = ex;
        int g = (b << BKT_SH) + t;
        if (g < NN) { rp[g] = s + ex; rpe[g] = s + cnt[t]; }
    }
    __syncthreads();
    for (int i = t; i < n; i += 256) {
        int2 v = sm[i];
        int  r = (v.x >> 18) & 0x1FF;
        if (r < BKT_RW) {
            int p = atomicAdd(&cur[r], 1);
            packed[s + p] = make_int2(v.x & 0x3FFFF, v.y);
        }
    }
}

// ---------------- gather SpMM, 4 rows/wave, quarter-wave per row ----------------
template <int OUT_BF16>
__global__ __launch_bounds__(256) void spmm_q(const int* __restrict__ rp,
                                              const int* __restrict__ rpe,
                                              const int2* __restrict__ packed,
                                              const uint2* __restrict__ ein,
                                              uint2* __restrict__ out_bf,
                                              float4* __restrict__ out_f32, int n) {
    int wave = (blockIdx.x * 256 + threadIdx.x) >> 6;
    int lane = threadIdx.x & 63;
    int l    = lane & 15;
    int row  = wave * 4 + (lane >> 4);

    float ax = 0.f, ay = 0.f, az = 0.f, aw = 0.f;
    int s = 0, e = 0;
    if (row < n) { s = rp[row]; e = rpe[row]; }

    for (int base = s; base < e; base += 16) {
        int cnt = e - base; if (cnt > 16) cnt = 16;
        int2 ev = make_int2(0, 0);
        if (l < cnt) ev = packed[base + l];
        int k = 0;
        for (; k + 4 <= cnt; k += 4) {
            int   c0 = __shfl(ev.x, k,     16), c1 = __shfl(ev.x, k + 1, 16);
            int   c2 = __shfl(ev.x, k + 2, 16), c3 = __shfl(ev.x, k + 3, 16);
            float v0 = __int_as_float(__shfl(ev.y, k,     16));
            float v1 = __int_as_float(__shfl(ev.y, k + 1, 16));
            float v2 = __int_as_float(__shfl(ev.y, k + 2, 16));
            float v3 = __int_as_float(__shfl(ev.y, k + 3, 16));
            uint2 g0 = ein[c0 * 16 + l];
            uint2 g1 = ein[c1 * 16 + l];
            uint2 g2 = ein[c2 * 16 + l];
            uint2 g3 = ein[c3 * 16 + l];
            ax += v0 * bf_lo(g0.x); ay += v0 * bf_hi(g0.x);
            az += v0 * bf_lo(g0.y); aw += v0 * bf_hi(g0.y);
            ax += v1 * bf_lo(g1.x); ay += v1 * bf_hi(g1.x);
            az += v1 * bf_lo(g1.y); aw += v1 * bf_hi(g1.y);
            ax += v2 * bf_lo(g2.x); ay += v2 * bf_hi(g2.x);
            az += v2 * bf_lo(g2.y); aw += v2 * bf_hi(g2.y);
            ax += v3 * bf_lo(g3.x); ay += v3 * bf_hi(g3.x);
            az += v3 * bf_lo(g3.y); aw += v3 * bf_hi(g3.y);
        }
        for (; k + 2 <= cnt; k += 2) {
            int   c0 = __shfl(ev.x, k, 16), c1 = __shfl(ev.x, k + 1, 16);
            float v0 = __int_as_float(__shfl(ev.y, k,     16));
            float v1 = __int_as_float(__shfl(ev.y, k + 1, 16));
            uint2 g0 = ein[c0 * 16 + l];
            uint2 g1 = ein[c1 * 16 + l];
            ax += v0 * bf_lo(g0.x); ay += v0 * bf_hi(g0.x);
            az += v0 * bf_lo(g0.y); aw += v0 * bf_hi(g0.y);
            ax += v1 * bf_lo(g1.x); ay += v1 * bf_hi(g1.x);
            az += v1 * bf_lo(g1.y); aw += v1 * bf_hi(g1.y);
        }
        if (k < cnt) {
            int   c0 = __shfl(ev.x, k, 16);
            float v0 = __int_as_float(__shfl(ev.y, k, 16));
            uint2 g0 = ein[c0 * 16 + l];
            ax += v0 * bf_lo(g0.x); ay += v0 * bf_hi(g0.x);
            az += v0 * bf_lo(g0.y); aw += v0 * bf_hi(g0.y);
        }
    }
    if (row < n) {
        if (OUT_BF16) {
            out_bf[(size_t)row * 16 + l] =
                make_uint2(pack2_bf16_rne(ax, ay), pack2_bf16_rne(az, aw));
        } else {
            out_f32[(size_t)row * 16 + l] = make_float4(ax, ay, az, aw);
        }
    }
}

// ---------------- fallback scatter SpMM (atomic path) ----------------
__global__ __launch_bounds__(256) void spmm_scatter(const int* __restrict__ rows,
                                                    const int* __restrict__ cols,
                                                    const float* __restrict__ vals,
                                                    const float* __restrict__ ein,
                                                    float* __restrict__ eout, int E) {
    int gid  = blockIdx.x * blockDim.x + threadIdx.x;
    int wid  = gid >> 6;
    int lane = threadIdx.x & 63;
    int nw   = (gridDim.x * blockDim.x) >> 6;
    for (int e = wid; e < E; e += nw) {
        int   r = rows[e];
        int   c = cols[e];
        float v = vals[e];
        float x = ein[(size_t)c * D + lane];
        unsafeAtomicAdd(&eout[(size_t)r * D + lane], v * x);
    }
}

// ---------------- MFMA fused 2-layer residual MLP + LayerNorm, in-place ----------------
__global__ __launch_bounds__(256) void mlp_mfma(float* __restrict__ e,
                                                const float* __restrict__ Ws,
                                                const float* __restrict__ bs,
                                                const float* __restrict__ gamma,
                                                const float* __restrict__ beta) {
    __shared__ float xp[4][16][68];
    int t  = threadIdx.x;
    int wv = t >> 6;
    int fr = t & 15;
    int fq = (t & 63) >> 4;

    short8 wh[2][4][2], wl[2][4][2];
    #pragma unroll
    for (int l = 0; l < 2; ++l)
        #pragma unroll
        for (int nt = 0; nt < 4; ++nt)
            #pragma unroll
            for (int kk = 0; kk < 2; ++kk) {
                const float* src = Ws + l * 4096 + (nt * 16 + fr) * 64 + kk * 32 + fq * 8;
                float4 a = *(const float4*)src;
                float4 b = *(const float4*)(src + 4);
                float v[8] = {a.x, a.y, a.z, a.w, b.x, b.y, b.z, b.w};
                short8 H, L;
                #pragma unroll
                for (int j = 0; j < 8; ++j) {
                    unsigned short hh = f32_to_bf16_rne(v[j]);
                    H[j] = hh;
                    L[j] = f32_to_bf16_rne(v[j] - bf16_bits_to_f32(hh));
                }
                wh[l][nt][kk] = H;
                wl[l][nt][kk] = L;
            }
    float bia0[4], bia1[4], gam[4], bet[4];
    #pragma unroll
    for (int nt = 0; nt < 4; ++nt) {
        bia0[nt] = bs[nt * 16 + fr];
        bia1[nt] = bs[64 + nt * 16 + fr];
        gam[nt]  = gamma[nt * 16 + fr];
        bet[nt]  = beta[nt * 16 + fr];
    }

    int wgid = blockIdx.x * 4 + wv;
    int nwv  = gridDim.x * 4;
    for (int tile = wgid; tile < NTILE; tile += nwv) {
        float* base = e + (size_t)tile * 16 * D;

        short8 xh[2], xl[2];
        #pragma unroll
        for (int kk = 0; kk < 2; ++kk) {
            const float* s = base + fr * D + kk * 32 + fq * 8;
            float4 a = *(const float4*)s;
            float4 b = *(const float4*)(s + 4);
            float v[8] = {a.x, a.y, a.z, a.w, b.x, b.y, b.z, b.w};
            #pragma unroll
            for (int j = 0; j < 8; ++j) {
                unsigned short hh = f32_to_bf16_rne(v[j]);
                xh[kk][j] = hh;
                xl[kk][j] = f32_to_bf16_rne(v[j] - bf16_bits_to_f32(hh));
            }
        }
        float xr[4][4];
        #pragma unroll
        for (int nt = 0; nt < 4; ++nt)
            #pragma unroll
            for (int j = 0; j < 4; ++j)
                xr[nt][j] = base[(fq * 4 + j) * D + nt * 16 + fr];

        f32x4 acc[4];
        #pragma unroll
        for (int nt = 0; nt < 4; ++nt) {
            acc[nt] = f32x4{bia0[nt], bia0[nt], bia0[nt], bia0[nt]};
            #pragma unroll
            for (int kk = 0; kk < 2; ++kk) {
                acc[nt] = __builtin_amdgcn_mfma_f32_16x16x32_bf16(xl[kk], wh[0][nt][kk], acc[nt], 0, 0, 0);
                acc[nt] = __builtin_amdgcn_mfma_f32_16x16x32_bf16(xh[kk], wl[0][nt][kk], acc[nt], 0, 0, 0);
                acc[nt] = __builtin_amdgcn_mfma_f32_16x16x32_bf16(xh[kk], wh[0][nt][kk], acc[nt], 0, 0, 0);
            }
        }
        float y1[4][4];
        #pragma unroll
        for (int nt = 0; nt < 4; ++nt)
            #pragma unroll
            for (int j = 0; j < 4; ++j) {
                y1[nt][j] = fmaxf(acc[nt][j], 0.f) + xr[nt][j];
                xp[wv][fq * 4 + j][nt * 16 + fr] = y1[nt][j];
            }

        #pragma unroll
        for (int kk = 0; kk < 2; ++kk) {
            const float* s = &xp[wv][fr][kk * 32 + fq * 8];
            float4 a = *(const float4*)s;
            float4 b = *(const float4*)(s + 4);
            float v[8] = {a.x, a.y, a.z, a.w, b.x, b.y, b.z, b.w};
            #pragma unroll
            for (int j = 0; j < 8; ++j) {
                unsigned short hh = f32_to_bf16_rne(v[j]);
                xh[kk][j] = hh;
                xl[kk][j] = f32_to_bf16_rne(v[j] - bf16_bits_to_f32(hh));
            }
        }

        #pragma unroll
        for (int nt = 0; nt < 4; ++nt) {
            acc[nt] = f32x4{bia1[nt], bia1[nt], bia1[nt], bia1[nt]};
            #pragma unroll
            for (int kk = 0; kk < 2; ++kk) {
                acc[nt] = __builtin_amdgcn_mfma_f32_16x16x32_bf16(xl[kk], wh[1][nt][kk], acc[nt], 0, 0, 0);
                acc[nt] = __builtin_amdgcn_mfma_f32_16x16x32_bf16(xh[kk], wl[1][nt][kk], acc[nt], 0, 0, 0);
                acc[nt] = __builtin_amdgcn_mfma_f32_16x16x32_bf16(xh[kk], wh[1][nt][kk], acc[nt], 0, 0, 0);
            }
        }
        float y2[4][4];
        #pragma unroll
        for (int nt = 0; nt < 4; ++nt)
            #pragma unroll
            for (int j = 0; j < 4; ++j)
                y2[nt][j] = fmaxf(acc[nt][j], 0.f) + y1[nt][j];

        float sm[4], sq[4];
        #pragma unroll
        for (int j = 0; j < 4; ++j) {
            float s0 = 0.f, q0 = 0.f;
            #pragma unroll
            for (int nt = 0; nt < 4; ++nt) { s0 += y2[nt][j]; q0 += y2[nt][j] * y2[nt][j]; }
            sm[j] = s0; sq[j] = q0;
        }
        #pragma unroll
        for (int off = 1; off < 16; off <<= 1) {
            #pragma unroll
            for (int j = 0; j < 4; ++j) {
                sm[j] += __shfl_xor(sm[j], off);
                sq[j] += __shfl_xor(sq[j], off);
            }
        }
        #pragma unroll
        for (int j = 0; j < 4; ++j) {
            float mu  = sm[j] * (1.f / 64.f);
            float var = sq[j] * (1.f / 64.f) - mu * mu;
            float rs  = rsqrtf(var + 1e-5f);
            #pragma unroll
            for (int nt = 0; nt < 4; ++nt)
                base[(fq * 4 + j) * D + nt * 16 + fr] =
                    (y2[nt][j] - mu) * rs * gam[nt] + bet[nt];
        }
    }
}

template <int ALIGN>
static void run_csr(const int* rows, const int* cols, const float* vals,
                    const float* ini, float* out, char* w, int E, size_t packed_cap,
                    hipStream_t stream) {
    size_t inibf_b  = (size_t)NN * 32 * 4;
    size_t e1bf_b   = inibf_b;
    size_t packed_b = packed_cap * 8;
    size_t rp_b     = (((size_t)NN + 1) * 4 + 63) & ~(size_t)63;
    size_t rpe_b    = (ALIGN > 1) ? rp_b : 0;
    size_t bsrt_b   = (((size_t)NBKT + 1) * 4 + 63) & ~(size_t)63;
    size_t pad_b    = (size_t)NBKT * CPAD * 4;

    unsigned* ini_bf   = (unsigned*)w;  w += inibf_b;
    unsigned* e1_bf    = (unsigned*)w;  w += e1bf_b;
    int2*     packed   = (int2*)w;      w += packed_b;
    int*      rp       = (int*)w;       w += rp_b;
    int*      rpe      = (ALIGN > 1) ? (int*)w : rp + 1;  w += rpe_b;
    int*      bktstart = (int*)w;       w += bsrt_b;
    int*      tot_p    = (int*)w;       w += pad_b;
    int*      cursor_p = (int*)w;

    int epb = (E + NCHUNK - 1) / NCHUNK;
    cvt_bf16<<<2048, 256, 0, stream>>>((const float2*)ini, ini_bf, NN * 32);
    zero_i<<<(NBKT * CPAD + 255) / 256, 256, 0, stream>>>(tot_p, NBKT * CPAD);
    bkt_count<ALIGN><<<NCHUNK, 1024, 0, stream>>>(rows, tot_p, E, epb);
    bkt_scan<<<1, 1024, 0, stream>>>(tot_p, bktstart, cursor_p);
    scatter_l1<ALIGN><<<NCHUNK, 1024, 0, stream>>>(rows, cols, vals, cursor_p, packed, E, epb);
    sort_l2<<<NBKT, 256, 0, stream>>>(bktstart, packed, rp, rpe);

    int waves = (NN + 3) / 4;
    int blocks = (waves + 3) / 4;
    spmm_q<1><<<blocks, 256, 0, stream>>>(rp, rpe, packed, (const uint2*)ini_bf,
                                          (uint2*)e1_bf, nullptr, NN);
    spmm_q<0><<<blocks, 256, 0, stream>>>(rp, rpe, packed, (const uint2*)e1_bf,
                                          nullptr, (float4*)out, NN);
}

extern "C" void kernel_launch(void* const* d_in, const int* in_sizes, int n_in,
                              void* d_out, int out_size, void* d_ws, size_t ws_size,
                              hipStream_t stream) {
    const int*   rows  = (const int*)d_in[0];
    const int*   cols  = (const int*)d_in[1];
    const float* vals  = (const float*)d_in[2];
    const float* ini   = (const float*)d_in[3];
    const float* Ws    = (const float*)d_in[4];
    const float* bs    = (const float*)d_in[5];
    const float* gamma = (const float*)d_in[6];
    const float* beta  = (const float*)d_in[7];
    float* out = (float*)d_out;
    int E = in_sizes[0];

    size_t inibf_b = (size_t)NN * 32 * 4;
    size_t rp_b    = (((size_t)NN + 1) * 4 + 63) & ~(size_t)63;
    size_t bsrt_b  = (((size_t)NBKT + 1) * 4 + 63) & ~(size_t)63;
    size_t pad_b   = (size_t)NBKT * CPAD * 4;
    size_t cap8    = (size_t)E + (size_t)NBKT * NCHUNK * 7;   // worst-case pads
    size_t cap1    = (size_t)E;
    size_t need8   = 2 * inibf_b + cap8 * 8 + 2 * rp_b + bsrt_b + 2 * pad_b;
    size_t need1   = 2 * inibf_b + cap1 * 8 + rp_b + bsrt_b + 2 * pad_b;

    if (ws_size >= need8) {
        run_csr<8>(rows, cols, vals, ini, out, (char*)d_ws, E, cap8, stream);
    } else if (ws_size >= need1) {
        run_csr<1>(rows, cols, vals, ini, out, (char*)d_ws, E, cap1, stream);
    } else {
        float* e1 = (float*)d_ws;
        int n4 = out_size / 4;
        int zb = (n4 + 255) / 256;
        zero_f4<<<zb, 256, 0, stream>>>((float4*)e1,  n4);
        zero_f4<<<zb, 256, 0, stream>>>((float4*)out, n4);
        spmm_scatter<<<12800, 256, 0, stream>>>(rows, cols, vals, ini, e1, E);
        spmm_scatter<<<12800, 256, 0, stream>>>(rows, cols, vals, e1, out, E);
    }

    mlp_mfma<<<1563, 256, 0, stream>>>(out, Ws, bs, gamma, beta);
}

// Round 11
// 234.037 us; speedup vs baseline: 1.2960x; 1.1889x over previous
//
#include <hip/hip_runtime.h>
#include <hip/hip_bf16.h>

#define NN      200000
#define D       64
#define NTILE   12500        // NN / 16
#define BKT_SH  8            // 256 rows per bucket
#define BKT_RW  256
#define NBKT    782          // ceil(NN / 256)
#define NCHUNK  256          // edge-pass blocks (1024 threads each); epb = 12500
#define L2CAP   6656         // max edges/bucket staged in LDS (53 KB)
#define CPAD    16           // cursor padding (ints) -> one 64B line per bucket
#define RSENT   256          // sentinel r_local for pad edges

typedef __attribute__((ext_vector_type(8))) short short8;
typedef __attribute__((ext_vector_type(4))) short short4v;
typedef __attribute__((ext_vector_type(4))) float f32x4;

__device__ inline unsigned short f32_to_bf16_rne(float x) {
    unsigned u = __float_as_uint(x);
    unsigned r = u + 0x7FFFu + ((u >> 16) & 1u);
    return (unsigned short)(r >> 16);
}
__device__ inline float bf16_bits_to_f32(unsigned short h) {
    return __uint_as_float(((unsigned)h) << 16);
}
__device__ inline unsigned pack2_bf16_rne(float lo, float hi) {
    unsigned a = __float_as_uint(lo);
    unsigned b = __float_as_uint(hi);
    a = a + 0x7FFFu + ((a >> 16) & 1u);
    b = b + 0x7FFFu + ((b >> 16) & 1u);
    return (a >> 16) | (b & 0xFFFF0000u);
}
__device__ inline float bf_lo(unsigned u) { return __uint_as_float(u << 16); }
__device__ inline float bf_hi(unsigned u) { return __uint_as_float(u & 0xFFFF0000u); }

// ---------------- utility kernels ----------------
__global__ __launch_bounds__(256) void zero_f4(float4* __restrict__ p, int n4) {
    int i = blockIdx.x * blockDim.x + threadIdx.x;
    if (i < n4) p[i] = make_float4(0.f, 0.f, 0.f, 0.f);
}
__global__ __launch_bounds__(256) void zero_i(int* __restrict__ p, int n) {
    int i = blockIdx.x * blockDim.x + threadIdx.x;
    if (i < n) p[i] = 0;
}
__global__ __launch_bounds__(256) void cvt_bf16(const float2* __restrict__ in,
                                                unsigned* __restrict__ out, int n) {
    int stride = gridDim.x * blockDim.x;
    for (int i = blockIdx.x * blockDim.x + threadIdx.x; i < n; i += stride) {
        float2 v = in[i];
        out[i] = pack2_bf16_rne(v.x, v.y);
    }
}

// ---------------- pass 1: ALIGNED bucket totals (same partition as scatter) ----------------
template <int ALIGN>
__global__ __launch_bounds__(1024) void bkt_count(const int* __restrict__ rows,
                                                  int* __restrict__ tot_p,
                                                  int E, int epb) {
    __shared__ int h[NBKT];
    int t = threadIdx.x;
    for (int i = t; i < NBKT; i += 1024) h[i] = 0;
    __syncthreads();
    int start = blockIdx.x * epb;
    int end   = min(E, start + epb);
    for (int e = start + t; e < end; e += 1024)
        atomicAdd(&h[rows[e] >> BKT_SH], 1);
    __syncthreads();
    for (int i = t; i < NBKT; i += 1024) {
        int c   = h[i];
        int res = (c + ALIGN - 1) & ~(ALIGN - 1);
        if (res) atomicAdd(&tot_p[i * CPAD], res);
    }
}

// ---------------- pass 2: single-block scan over aligned bucket totals ----------------
__global__ __launch_bounds__(1024) void bkt_scan(const int* __restrict__ tot_p,
                                                 int* __restrict__ bktstart,
                                                 int* __restrict__ cursor_p) {
    __shared__ int s[1024];
    int t = threadIdx.x;
    int v = (t < NBKT) ? tot_p[t * CPAD] : 0;
    s[t] = v;
    __syncthreads();
    #pragma unroll
    for (int d = 1; d < 1024; d <<= 1) {
        int a = (t >= d) ? s[t - d] : 0;
        __syncthreads();
        s[t] += a;
        __syncthreads();
    }
    if (t < NBKT) {
        int ex = s[t] - v;
        bktstart[t] = ex;
        cursor_p[t * CPAD] = ex;
    }
    if (t == 0) bktstart[NBKT] = s[1023];
}

// ---------------- pass 3: scatter into 64B-aligned bucket runs ----------------
template <int ALIGN>
__global__ __launch_bounds__(1024) void scatter_l1(const int* __restrict__ rows,
                                                   const int* __restrict__ cols,
                                                   const float* __restrict__ vals,
                                                   int* __restrict__ cursor_p,
                                                   int2* __restrict__ packed,
                                                   int E, int epb) {
    __shared__ int h[NBKT];
    __shared__ int base[NBKT];
    int t = threadIdx.x;
    for (int i = t; i < NBKT; i += 1024) h[i] = 0;
    __syncthreads();
    int start = blockIdx.x * epb;
    int end   = min(E, start + epb);
    for (int e = start + t; e < end; e += 1024)
        atomicAdd(&h[rows[e] >> BKT_SH], 1);
    __syncthreads();
    for (int i = t; i < NBKT; i += 1024) {
        int c   = h[i];
        int res = (c + ALIGN - 1) & ~(ALIGN - 1);
        int b0  = res ? atomicAdd(&cursor_p[i * CPAD], res) : 0;
        base[i] = b0;
        for (int j = c; j < res; ++j)            // sentinel pads (never consumed)
            packed[b0 + j] = make_int2(RSENT << 18, 0);
        h[i] = 0;                                // reuse as run cursor
    }
    __syncthreads();
    for (int e = start + t; e < end; e += 1024) {
        int r = rows[e];
        int b = r >> BKT_SH;
        int p = base[b] + atomicAdd(&h[b], 1);
        packed[p] = make_int2(cols[e] | ((r & (BKT_RW - 1)) << 18),
                              __float_as_int(vals[e]));
    }
}

// ---------------- pass 4: per-bucket in-place sort to exact CSR (drops pads) ----------------
__global__ __launch_bounds__(256) void sort_l2(const int* __restrict__ bktstart,
                                               int2* __restrict__ packed,
                                               int* __restrict__ rp,
                                               int* __restrict__ rpe) {
    __shared__ int2 sm[L2CAP];
    __shared__ int  cnt[BKT_RW];
    __shared__ int  cur[BKT_RW];
    int b = blockIdx.x;
    int s = bktstart[b];
    int e = bktstart[b + 1];
    int n = e - s;
    if (n > L2CAP) n = L2CAP;
    int t = threadIdx.x;
    cnt[t] = 0;
    __syncthreads();
    for (int i = t; i < n; i += 256) {
        int2 v = packed[s + i];
        sm[i] = v;
        int r = (v.x >> 18) & 0x1FF;
        if (r < BKT_RW) atomicAdd(&cnt[r], 1);
    }
    __syncthreads();
    #pragma unroll
    for (int d = 1; d < BKT_RW; d <<= 1) {
        int a = (t >= d) ? cnt[t - d] : 0;
        __syncthreads();
        cnt[t] += a;
        __syncthreads();
    }
    {
        int ex = t ? cnt[t - 1] : 0;
        cur[t] = ex;
        int g = (b << BKT_SH) + t;
        if (g < NN) { rp[g] = s + ex; rpe[g] = s + cnt[t]; }
    }
    __syncthreads();
    for (int i = t; i < n; i += 256) {
        int2 v = sm[i];
        int  r = (v.x >> 18) & 0x1FF;
        if (r < BKT_RW) {
            int p = atomicAdd(&cur[r], 1);
            packed[s + p] = make_int2(v.x & 0x3FFFF, v.y);
        }
    }
}

// ---------------- gather SpMM, 4 rows/wave, quarter-wave per row ----------------
template <int OUT_BF16>
__global__ __launch_bounds__(256) void spmm_q(const int* __restrict__ rp,
                                              const int* __restrict__ rpe,
                                              const int2* __restrict__ packed,
                                              const uint2* __restrict__ ein,
                                              uint2* __restrict__ out_bf,
                                              float4* __restrict__ out_f32, int n) {
    int wave = (blockIdx.x * 256 + threadIdx.x) >> 6;
    int lane = threadIdx.x & 63;
    int l    = lane & 15;
    int row  = wave * 4 + (lane >> 4);

    float ax = 0.f, ay = 0.f, az = 0.f, aw = 0.f;
    int s = 0, e = 0;
    if (row < n) { s = rp[row]; e = rpe[row]; }

    for (int base = s; base < e; base += 16) {
        int cnt = e - base; if (cnt > 16) cnt = 16;
        int2 ev = make_int2(0, 0);
        if (l < cnt) ev = packed[base + l];
        int k = 0;
        for (; k + 4 <= cnt; k += 4) {
            int   c0 = __shfl(ev.x, k,     16), c1 = __shfl(ev.x, k + 1, 16);
            int   c2 = __shfl(ev.x, k + 2, 16), c3 = __shfl(ev.x, k + 3, 16);
            float v0 = __int_as_float(__shfl(ev.y, k,     16));
            float v1 = __int_as_float(__shfl(ev.y, k + 1, 16));
            float v2 = __int_as_float(__shfl(ev.y, k + 2, 16));
            float v3 = __int_as_float(__shfl(ev.y, k + 3, 16));
            uint2 g0 = ein[c0 * 16 + l];
            uint2 g1 = ein[c1 * 16 + l];
            uint2 g2 = ein[c2 * 16 + l];
            uint2 g3 = ein[c3 * 16 + l];
            ax += v0 * bf_lo(g0.x); ay += v0 * bf_hi(g0.x);
            az += v0 * bf_lo(g0.y); aw += v0 * bf_hi(g0.y);
            ax += v1 * bf_lo(g1.x); ay += v1 * bf_hi(g1.x);
            az += v1 * bf_lo(g1.y); aw += v1 * bf_hi(g1.y);
            ax += v2 * bf_lo(g2.x); ay += v2 * bf_hi(g2.x);
            az += v2 * bf_lo(g2.y); aw += v2 * bf_hi(g2.y);
            ax += v3 * bf_lo(g3.x); ay += v3 * bf_hi(g3.x);
            az += v3 * bf_lo(g3.y); aw += v3 * bf_hi(g3.y);
        }
        for (; k + 2 <= cnt; k += 2) {
            int   c0 = __shfl(ev.x, k, 16), c1 = __shfl(ev.x, k + 1, 16);
            float v0 = __int_as_float(__shfl(ev.y, k,     16));
            float v1 = __int_as_float(__shfl(ev.y, k + 1, 16));
            uint2 g0 = ein[c0 * 16 + l];
            uint2 g1 = ein[c1 * 16 + l];
            ax += v0 * bf_lo(g0.x); ay += v0 * bf_hi(g0.x);
            az += v0 * bf_lo(g0.y); aw += v0 * bf_hi(g0.y);
            ax += v1 * bf_lo(g1.x); ay += v1 * bf_hi(g1.x);
            az += v1 * bf_lo(g1.y); aw += v1 * bf_hi(g1.y);
        }
        if (k < cnt) {
            int   c0 = __shfl(ev.x, k, 16);
            float v0 = __int_as_float(__shfl(ev.y, k, 16));
            uint2 g0 = ein[c0 * 16 + l];
            ax += v0 * bf_lo(g0.x); ay += v0 * bf_hi(g0.x);
            az += v0 * bf_lo(g0.y); aw += v0 * bf_hi(g0.y);
        }
    }
    if (row < n) {
        if (OUT_BF16) {
            out_bf[(size_t)row * 16 + l] =
                make_uint2(pack2_bf16_rne(ax, ay), pack2_bf16_rne(az, aw));
        } else {
            out_f32[(size_t)row * 16 + l] = make_float4(ax, ay, az, aw);
        }
    }
}

// ---------------- fallback scatter SpMM (atomic path) ----------------
__global__ __launch_bounds__(256) void spmm_scatter(const int* __restrict__ rows,
                                                    const int* __restrict__ cols,
                                                    const float* __restrict__ vals,
                                                    const float* __restrict__ ein,
                                                    float* __restrict__ eout, int E) {
    int gid  = blockIdx.x * blockDim.x + threadIdx.x;
    int wid  = gid >> 6;
    int lane = threadIdx.x & 63;
    int nw   = (gridDim.x * blockDim.x) >> 6;
    for (int e = wid; e < E; e += nw) {
        int   r = rows[e];
        int   c = cols[e];
        float v = vals[e];
        float x = ein[(size_t)c * D + lane];
        unsafeAtomicAdd(&eout[(size_t)r * D + lane], v * x);
    }
}

// ---------------- MFMA fused MLP+LN v2: W in LDS (block-shared), coalesced LDS-staged tiles ----------------
__global__ __launch_bounds__(256) void mlp_v2(float* __restrict__ e,
                                              const float* __restrict__ Ws,
                                              const float* __restrict__ bs,
                                              const float* __restrict__ gamma,
                                              const float* __restrict__ beta) {
    __shared__ unsigned short wlds[2][64][72];   // [layer][n][k], padded rows (144B)
    __shared__ float tb[4][16][68];              // per-wave tile, padded rows (272B)

    int t    = threadIdx.x;
    int wv   = t >> 6;
    int lane = t & 63;
    int fr   = t & 15;
    int fq   = lane >> 4;

    // stage W (both layers) into LDS as bf16 -- 256 threads x 4 floats = 1024/sweep
    for (int i = t * 4; i < 2 * 64 * 64; i += 1024) {
        float4 f = *(const float4*)(Ws + i);
        int l = i >> 12, r = (i >> 6) & 63, c = i & 63;
        short4v s4;
        s4[0] = (short)f32_to_bf16_rne(f.x);
        s4[1] = (short)f32_to_bf16_rne(f.y);
        s4[2] = (short)f32_to_bf16_rne(f.z);
        s4[3] = (short)f32_to_bf16_rne(f.w);
        *(short4v*)&wlds[l][r][c] = s4;
    }
    __syncthreads();

    float bia[2][4], gam[4], bet[4];
    #pragma unroll
    for (int nt = 0; nt < 4; ++nt) {
        bia[0][nt] = bs[nt * 16 + fr];
        bia[1][nt] = bs[64 + nt * 16 + fr];
        gam[nt]    = gamma[nt * 16 + fr];
        bet[nt]    = beta[nt * 16 + fr];
    }

    float (*tw)[68] = tb[wv];

    for (int tile = blockIdx.x * 4 + wv; tile < NTILE; tile += gridDim.x * 4) {
        float* base = e + (size_t)tile * 1024;

        // coalesced stage-in
        #pragma unroll
        for (int it = 0; it < 4; ++it) {
            int idx = it * 256 + lane * 4;
            *(float4*)&tw[idx >> 6][idx & 63] = *(const float4*)(base + idx);
        }

        #pragma unroll
        for (int l = 0; l < 2; ++l) {
            short8 xh[2], xl[2];
            #pragma unroll
            for (int kk = 0; kk < 2; ++kk) {
                const float* s = &tw[fr][kk * 32 + fq * 8];
                float4 a = *(const float4*)s;
                float4 b4 = *(const float4*)(s + 4);
                float v[8] = {a.x, a.y, a.z, a.w, b4.x, b4.y, b4.z, b4.w};
                #pragma unroll
                for (int j = 0; j < 8; ++j) {
                    unsigned short hh = f32_to_bf16_rne(v[j]);
                    xh[kk][j] = (short)hh;
                    xl[kk][j] = (short)f32_to_bf16_rne(v[j] - bf16_bits_to_f32(hh));
                }
            }
            f32x4 acc[4];
            #pragma unroll
            for (int nt = 0; nt < 4; ++nt) {
                float bb = bia[l][nt];
                acc[nt] = f32x4{bb, bb, bb, bb};
                #pragma unroll
                for (int kk = 0; kk < 2; ++kk) {
                    short8 w8 = *(const short8*)&wlds[l][nt * 16 + fr][kk * 32 + fq * 8];
                    acc[nt] = __builtin_amdgcn_mfma_f32_16x16x32_bf16(xl[kk], w8, acc[nt], 0, 0, 0);
                    acc[nt] = __builtin_amdgcn_mfma_f32_16x16x32_bf16(xh[kk], w8, acc[nt], 0, 0, 0);
                }
            }
            #pragma unroll
            for (int nt = 0; nt < 4; ++nt)
                #pragma unroll
                for (int j = 0; j < 4; ++j) {
                    float* cell = &tw[fq * 4 + j][nt * 16 + fr];
                    *cell = fmaxf(acc[nt][j], 0.f) + *cell;
                }
        }

        // LayerNorm: read y2 back, reduce across low-4 lane bits
        float y2[4][4], sm[4], sq[4];
        #pragma unroll
        for (int j = 0; j < 4; ++j) { sm[j] = 0.f; sq[j] = 0.f; }
        #pragma unroll
        for (int nt = 0; nt < 4; ++nt)
            #pragma unroll
            for (int j = 0; j < 4; ++j) {
                float v = tw[fq * 4 + j][nt * 16 + fr];
                y2[nt][j] = v;
                sm[j] += v; sq[j] += v * v;
            }
        #pragma unroll
        for (int off = 1; off < 16; off <<= 1) {
            #pragma unroll
            for (int j = 0; j < 4; ++j) {
                sm[j] += __shfl_xor(sm[j], off);
                sq[j] += __shfl_xor(sq[j], off);
            }
        }
        #pragma unroll
        for (int j = 0; j < 4; ++j) {
            float mu  = sm[j] * (1.f / 64.f);
            float var = sq[j] * (1.f / 64.f) - mu * mu;
            float rs  = rsqrtf(var + 1e-5f);
            #pragma unroll
            for (int nt = 0; nt < 4; ++nt)
                tw[fq * 4 + j][nt * 16 + fr] = (y2[nt][j] - mu) * rs * gam[nt] + bet[nt];
        }

        // coalesced stage-out
        #pragma unroll
        for (int it = 0; it < 4; ++it) {
            int idx = it * 256 + lane * 4;
            *(float4*)(base + idx) = *(const float4*)&tw[idx >> 6][idx & 63];
        }
    }
}

template <int ALIGN>
static void run_csr(const int* rows, const int* cols, const float* vals,
                    const float* ini, float* out, char* w, int E, size_t packed_cap,
                    hipStream_t stream) {
    size_t inibf_b  = (size_t)NN * 32 * 4;
    size_t e1bf_b   = inibf_b;
    size_t packed_b = packed_cap * 8;
    size_t rp_b     = (((size_t)NN + 1) * 4 + 63) & ~(size_t)63;
    size_t rpe_b    = (ALIGN > 1) ? rp_b : 0;
    size_t bsrt_b   = (((size_t)NBKT + 1) * 4 + 63) & ~(size_t)63;
    size_t pad_b    = (size_t)NBKT * CPAD * 4;

    unsigned* ini_bf   = (unsigned*)w;  w += inibf_b;
    unsigned* e1_bf    = (unsigned*)w;  w += e1bf_b;
    int2*     packed   = (int2*)w;      w += packed_b;
    int*      rp       = (int*)w;       w += rp_b;
    int*      rpe      = (ALIGN > 1) ? (int*)w : rp + 1;  w += rpe_b;
    int*      bktstart = (int*)w;       w += bsrt_b;
    int*      tot_p    = (int*)w;       w += pad_b;
    int*      cursor_p = (int*)w;

    int epb = (E + NCHUNK - 1) / NCHUNK;
    cvt_bf16<<<2048, 256, 0, stream>>>((const float2*)ini, ini_bf, NN * 32);
    zero_i<<<(NBKT * CPAD + 255) / 256, 256, 0, stream>>>(tot_p, NBKT * CPAD);
    bkt_count<ALIGN><<<NCHUNK, 1024, 0, stream>>>(rows, tot_p, E, epb);
    bkt_scan<<<1, 1024, 0, stream>>>(tot_p, bktstart, cursor_p);
    scatter_l1<ALIGN><<<NCHUNK, 1024, 0, stream>>>(rows, cols, vals, cursor_p, packed, E, epb);
    sort_l2<<<NBKT, 256, 0, stream>>>(bktstart, packed, rp, rpe);

    int waves = (NN + 3) / 4;
    int blocks = (waves + 3) / 4;
    spmm_q<1><<<blocks, 256, 0, stream>>>(rp, rpe, packed, (const uint2*)ini_bf,
                                          (uint2*)e1_bf, nullptr, NN);
    spmm_q<0><<<blocks, 256, 0, stream>>>(rp, rpe, packed, (const uint2*)e1_bf,
                                          nullptr, (float4*)out, NN);
}

extern "C" void kernel_launch(void* const* d_in, const int* in_sizes, int n_in,
                              void* d_out, int out_size, void* d_ws, size_t ws_size,
                              hipStream_t stream) {
    const int*   rows  = (const int*)d_in[0];
    const int*   cols  = (const int*)d_in[1];
    const float* vals  = (const float*)d_in[2];
    const float* ini   = (const float*)d_in[3];
    const float* Ws    = (const float*)d_in[4];
    const float* bs    = (const float*)d_in[5];
    const float* gamma = (const float*)d_in[6];
    const float* beta  = (const float*)d_in[7];
    float* out = (float*)d_out;
    int E = in_sizes[0];

    size_t inibf_b = (size_t)NN * 32 * 4;
    size_t rp_b    = (((size_t)NN + 1) * 4 + 63) & ~(size_t)63;
    size_t bsrt_b  = (((size_t)NBKT + 1) * 4 + 63) & ~(size_t)63;
    size_t pad_b   = (size_t)NBKT * CPAD * 4;
    size_t cap8    = (size_t)E + (size_t)NBKT * NCHUNK * 7;   // worst-case pads
    size_t cap1    = (size_t)E;
    size_t need8   = 2 * inibf_b + cap8 * 8 + 2 * rp_b + bsrt_b + 2 * pad_b;
    size_t need1   = 2 * inibf_b + cap1 * 8 + rp_b + bsrt_b + 2 * pad_b;

    if (ws_size >= need8) {
        run_csr<8>(rows, cols, vals, ini, out, (char*)d_ws, E, cap8, stream);
    } else if (ws_size >= need1) {
        run_csr<1>(rows, cols, vals, ini, out, (char*)d_ws, E, cap1, stream);
    } else {
        float* e1 = (float*)d_ws;
        int n4 = out_size / 4;
        int zb = (n4 + 255) / 256;
        zero_f4<<<zb, 256, 0, stream>>>((float4*)e1,  n4);
        zero_f4<<<zb, 256, 0, stream>>>((float4*)out, n4);
        spmm_scatter<<<12800, 256, 0, stream>>>(rows, cols, vals, ini, e1, E);
        spmm_scatter<<<12800, 256, 0, stream>>>(rows, cols, vals, e1, out, E);
    }

    mlp_v2<<<512, 256, 0, stream>>>(out, Ws, bs, gamma, beta);
}